// Round 3
// baseline (379.431 us; speedup 1.0000x reference)
//
#include <hip/hip_runtime.h>

// Problem: inputs (B=32, L=720, C=862) f32. Output (T=4, B, C, L) f32 spikes.
// x is broadcast across T => element-wise 4-step LIF. Memory-bound:
// 79.4 MB read + 317.8 MB write => ~63 us kernel roofline.
//
// R5: drop __builtin_nontemporal_store -> plain stores. R4 (t-major row
// stores) was exactly flat vs R3 (369.64 vs 369.67) => write-stream
// granularity falsified. The rocclr fill (plain stores, grid-strided,
// ~10% occupancy) hits 6.4 TB/s; our kernel ~2.3 TB/s. Remaining deltas
// vs fill: nt store policy, read/write mixing, LDS/barrier. This round
// isolates the nt flag: stores go through the normal L2 path. All other
// code byte-identical to R4.

#define B_DIM 32
#define L_DIM 720
#define C_DIM 862
#define T_STEPS 4
#define TC 16
#define SL 724   // LDS l-stride per c row (floats): %4==0 (b128), %8==4 (banks)

typedef float v2f __attribute__((ext_vector_type(2)));
typedef float v4f __attribute__((ext_vector_type(4)));

__device__ __forceinline__ void lif4(const v4f x, v4f s[T_STEPS]) {
    // LIF: v += (x - v)*0.5 ; s = (v>=1) ; v = s ? 0 : v   (exact ref arith)
    float v0 = 0.f, v1 = 0.f, v2 = 0.f, v3 = 0.f;
#pragma unroll
    for (int t = 0; t < T_STEPS; ++t) {
        v0 += (x.x - v0) * 0.5f;
        v1 += (x.y - v1) * 0.5f;
        v2 += (x.z - v2) * 0.5f;
        v3 += (x.w - v3) * 0.5f;
        v4f o;
        o.x = (v0 >= 1.0f) ? 1.0f : 0.0f;
        o.y = (v1 >= 1.0f) ? 1.0f : 0.0f;
        o.z = (v2 >= 1.0f) ? 1.0f : 0.0f;
        o.w = (v3 >= 1.0f) ? 1.0f : 0.0f;
        s[t] = o;
        v0 = (v0 >= 1.0f) ? 0.0f : v0;
        v1 = (v1 >= 1.0f) ? 0.0f : v1;
        v2 = (v2 >= 1.0f) ? 0.0f : v2;
        v3 = (v3 >= 1.0f) ? 0.0f : v3;
    }
}

__global__ __launch_bounds__(256)
void lif_repeat_encoder(const float* __restrict__ in, float* __restrict__ out) {
    __shared__ float sm[TC * SL];   // 46,336 B

    const int b   = blockIdx.y;
    const int c0  = blockIdx.x * TC;
    const int tid = threadIdx.x;

    const float* __restrict__ inb = in + (size_t)b * (L_DIM * C_DIM);

    // ---- Load phase: rows l, 2 consecutive c per lane (float2, 8B-aligned:
    // row stride 3448 B and c even keep %8==0). 8 lanes cover the 16-c tile
    // per row; 256 threads = 32 rows per round; 4 rounds batched for MLP.
    {
        const int cl2 = (tid & 7) << 1;   // c_local: 0,2,...,14
        const int c   = c0 + cl2;
        const int r0  = tid >> 3;         // 0..31
        if (c < C_DIM) {                  // tail tile (c0=848) has 14 cols: cl2=14 inactive
            for (int base = 0; base < L_DIM; base += 128) {
                v2f v[4];
#pragma unroll
                for (int u = 0; u < 4; ++u) {
                    const int r = base + r0 + 32 * u;
                    if (r < L_DIM)
                        v[u] = *(const v2f*)(inb + (size_t)r * C_DIM + c);
                }
#pragma unroll
                for (int u = 0; u < 4; ++u) {
                    const int r = base + r0 + 32 * u;
                    if (r < L_DIM) {
                        sm[cl2 * SL + r]       = v[u].x;
                        sm[(cl2 + 1) * SL + r] = v[u].y;
                    }
                }
            }
        }
    }
    __syncthreads();

    // ---- Store phase: wave w handles c_local = 4w..4w+3. Per (c,t) the wave
    // writes the FULL 720-float row (3 float4 bursts: 64+64+52 lanes)
    // back-to-back before switching t-plane.
    const int wave = tid >> 6;   // 0..3
    const int lane = tid & 63;
    const size_t plane = (size_t)B_DIM * C_DIM * L_DIM;

#pragma unroll
    for (int q = 0; q < 4; ++q) {
        const int cl = wave * 4 + q;
        const int c  = c0 + cl;
        if (c >= C_DIM) continue;

        const size_t rowbase = ((size_t)b * C_DIM + c) * L_DIM;
        const float* sr = sm + cl * SL;

        const int j0 = lane;              // < 180 always
        const int j1 = lane + 64;         // < 180 always (<=127)
        const int j2 = lane + 128;        // valid iff lane < 52
        const int j2c = (j2 < L_DIM / 4) ? j2 : (L_DIM / 4 - 1);  // clamp: keep LDS read in-bounds

        const v4f x0 = *(const v4f*)(sr + 4 * j0);
        const v4f x1 = *(const v4f*)(sr + 4 * j1);
        const v4f x2 = *(const v4f*)(sr + 4 * j2c);

        v4f s0[T_STEPS], s1[T_STEPS], s2[T_STEPS];
        lif4(x0, s0);
        lif4(x1, s1);
        lif4(x2, s2);

#pragma unroll
        for (int t = 0; t < T_STEPS; ++t) {
            float* op = out + (size_t)t * plane + rowbase;
            *(v4f*)(op + 4 * j0) = s0[t];
            *(v4f*)(op + 4 * j1) = s1[t];
            if (j2 < L_DIM / 4)
                *(v4f*)(op + 4 * j2) = s2[t];
        }
    }
}

extern "C" void kernel_launch(void* const* d_in, const int* in_sizes, int n_in,
                              void* d_out, int out_size, void* d_ws, size_t ws_size,
                              hipStream_t stream) {
    const float* in = (const float*)d_in[0];
    float* out = (float*)d_out;

    dim3 block(256, 1, 1);
    dim3 grid((C_DIM + TC - 1) / TC,   // 54
              B_DIM,                   // 32
              1);

    lif_repeat_encoder<<<grid, block, 0, stream>>>(in, out);
}

// Round 4
// 356.875 us; speedup vs baseline: 1.0632x; 1.0632x over previous
//
#include <hip/hip_runtime.h>

// Problem: inputs (B=32, L=720, C=862) f32. Output (T=4, B, C, L) f32 spikes.
// x is broadcast across T => element-wise 4-step LIF. Memory-bound:
// 79.4 MB read + 317.8 MB write => ~63 us kernel roofline (+ read straddle).
//
// R6: R4 base (t-major stores, nt restored — R5 showed plain stores neutral
// w/ noise; nt measured best twice) + XCD-chunked block remap.
// Why: input row stride 3448 B == 56 mod 64 -> each block's 64 B read
// segment straddles 2 lines (~2x read over-fetch); the straddled line is
// shared with the c-adjacent tile, but default dispatch round-robins
// adjacent blocks across the 8 non-coherent XCD L2s -> line fetched twice.
// Remap (bijective, 1728 = 8*216): xcd = wgid%8 owns b = 4*xcd..4*xcd+3;
// within an XCD all 54 c-tiles of one b-slab dispatch consecutively ->
// straddle partners co-resident in the same L2, slab read ~once/XCD.
// Store path / LDS layout / load pattern unchanged from R4.

#define B_DIM 32
#define L_DIM 720
#define C_DIM 862
#define T_STEPS 4
#define TC 16
#define SL 724   // LDS l-stride per c row (floats): %4==0 (b128), %8==4 (banks)

typedef float v2f __attribute__((ext_vector_type(2)));
typedef float v4f __attribute__((ext_vector_type(4)));

__device__ __forceinline__ void lif4(const v4f x, v4f s[T_STEPS]) {
    // LIF: v += (x - v)*0.5 ; s = (v>=1) ; v = s ? 0 : v   (exact ref arith)
    float v0 = 0.f, v1 = 0.f, v2 = 0.f, v3 = 0.f;
#pragma unroll
    for (int t = 0; t < T_STEPS; ++t) {
        v0 += (x.x - v0) * 0.5f;
        v1 += (x.y - v1) * 0.5f;
        v2 += (x.z - v2) * 0.5f;
        v3 += (x.w - v3) * 0.5f;
        v4f o;
        o.x = (v0 >= 1.0f) ? 1.0f : 0.0f;
        o.y = (v1 >= 1.0f) ? 1.0f : 0.0f;
        o.z = (v2 >= 1.0f) ? 1.0f : 0.0f;
        o.w = (v3 >= 1.0f) ? 1.0f : 0.0f;
        s[t] = o;
        v0 = (v0 >= 1.0f) ? 0.0f : v0;
        v1 = (v1 >= 1.0f) ? 0.0f : v1;
        v2 = (v2 >= 1.0f) ? 0.0f : v2;
        v3 = (v3 >= 1.0f) ? 0.0f : v3;
    }
}

__global__ __launch_bounds__(256)
void lif_repeat_encoder(const float* __restrict__ in, float* __restrict__ out) {
    __shared__ float sm[TC * SL];   // 46,336 B

    // ---- XCD-chunked bijective remap (grid 54x32 = 1728 = 8 XCD * 216).
    // HW round-robins linear wgid over XCDs: xcd = wgid % 8.
    // Within an XCD, consecutive n walk all 54 c-tiles of one b-slab first.
    const int wgid = blockIdx.x + (int)gridDim.x * blockIdx.y;
    const int xcd  = wgid & 7;
    const int n    = wgid >> 3;          // 0..215
    const int ct   = n % 54;             // c-tile within slab
    const int b    = (n / 54) + (xcd << 2);  // 4 b-slabs per XCD
    const int c0   = ct * TC;
    const int tid  = threadIdx.x;

    const float* __restrict__ inb = in + (size_t)b * (L_DIM * C_DIM);

    // ---- Load phase: rows l, 2 consecutive c per lane (float2, 8B-aligned:
    // row stride 3448 B and c even keep %8==0). 8 lanes cover the 16-c tile
    // per row; 256 threads = 32 rows per round; 4 rounds batched for MLP.
    {
        const int cl2 = (tid & 7) << 1;   // c_local: 0,2,...,14
        const int c   = c0 + cl2;
        const int r0  = tid >> 3;         // 0..31
        if (c < C_DIM) {                  // tail tile (c0=848) has 14 cols: cl2=14 inactive
            for (int base = 0; base < L_DIM; base += 128) {
                v2f v[4];
#pragma unroll
                for (int u = 0; u < 4; ++u) {
                    const int r = base + r0 + 32 * u;
                    if (r < L_DIM)
                        v[u] = *(const v2f*)(inb + (size_t)r * C_DIM + c);
                }
#pragma unroll
                for (int u = 0; u < 4; ++u) {
                    const int r = base + r0 + 32 * u;
                    if (r < L_DIM) {
                        sm[cl2 * SL + r]       = v[u].x;
                        sm[(cl2 + 1) * SL + r] = v[u].y;
                    }
                }
            }
        }
    }
    __syncthreads();

    // ---- Store phase: wave w handles c_local = 4w..4w+3. Per (c,t) the wave
    // writes the FULL 720-float row (3 float4 bursts: 64+64+52 lanes)
    // back-to-back before switching t-plane.
    const int wave = tid >> 6;   // 0..3
    const int lane = tid & 63;
    const size_t plane = (size_t)B_DIM * C_DIM * L_DIM;

#pragma unroll
    for (int q = 0; q < 4; ++q) {
        const int cl = wave * 4 + q;
        const int c  = c0 + cl;
        if (c >= C_DIM) continue;

        const size_t rowbase = ((size_t)b * C_DIM + c) * L_DIM;
        const float* sr = sm + cl * SL;

        const int j0 = lane;              // < 180 always
        const int j1 = lane + 64;         // < 180 always (<=127)
        const int j2 = lane + 128;        // valid iff lane < 52
        const int j2c = (j2 < L_DIM / 4) ? j2 : (L_DIM / 4 - 1);  // clamp: keep LDS read in-bounds

        const v4f x0 = *(const v4f*)(sr + 4 * j0);
        const v4f x1 = *(const v4f*)(sr + 4 * j1);
        const v4f x2 = *(const v4f*)(sr + 4 * j2c);

        v4f s0[T_STEPS], s1[T_STEPS], s2[T_STEPS];
        lif4(x0, s0);
        lif4(x1, s1);
        lif4(x2, s2);

#pragma unroll
        for (int t = 0; t < T_STEPS; ++t) {
            float* op = out + (size_t)t * plane + rowbase;
            __builtin_nontemporal_store(s0[t], (v4f*)(op + 4 * j0));
            __builtin_nontemporal_store(s1[t], (v4f*)(op + 4 * j1));
            if (j2 < L_DIM / 4)
                __builtin_nontemporal_store(s2[t], (v4f*)(op + 4 * j2));
        }
    }
}

extern "C" void kernel_launch(void* const* d_in, const int* in_sizes, int n_in,
                              void* d_out, int out_size, void* d_ws, size_t ws_size,
                              hipStream_t stream) {
    const float* in = (const float*)d_in[0];
    float* out = (float*)d_out;

    dim3 block(256, 1, 1);
    dim3 grid((C_DIM + TC - 1) / TC,   // 54
              B_DIM,                   // 32
              1);

    lif_repeat_encoder<<<grid, block, 0, stream>>>(in, out);
}